// Round 4
// baseline (43783.289 us; speedup 1.0000x reference)
//
#include <hip/hip_runtime.h>
#include <math.h>

// ---------------- problem constants ----------------
#define BB 8
#define TT 512
#define LL 20
#define NTHR 256
#define GRID 512
#define WK 64

typedef float f4 __attribute__((ext_vector_type(4)));
typedef unsigned long long ull;
typedef unsigned int u32;

__constant__ int c_dil[LL] = {1,2,4,8,16,32,64,128,256,512,
                              1,2,4,8,16,32,64,128,256,512};
// double-buffered rings: layer l has 2*d slots of 1024 floats (ring[0] unused)
__constant__ int c_roff[LL] = {-1,0,4096,12288,28672,61440,126976,258048,520192,1044480,
                               2093056,2095104,2099200,2107392,2123776,2156544,
                               2222080,2353152,2615296,3139584};

// ---------------- workspace layout (floats) ----------------
constexpr size_t OFF_RING = 0;          // 4,188,160 floats
constexpr size_t OFF_X    = 4188160;    // exchange: 4 slots * 768 float4
// election cells overlay mailbox slot 0 (f4[0..768) of OFF_X): slot 0 is first
// written at epoch 4, long after election completes. Cross-launch staleness is
// handled by per-launch hash tags.

// ---------------- election state (persistent, zero-init at load) --------
__device__ ull g_seq;
__device__ u32 g_xcnt[16];

// ---------------- LDS pool offsets (floats) ----------------
#define P_F      0        // [19][4][128]
#define P_WX     9728     // [2][1024] streamed causal slice (interleaved [g][2j+k])
#define P_WST    11776    // [512]
#define P_WSKIPC 12288    // [2][128]
#define P_WFC    12544    // [2][128]
#define P_WLOG   12800    // [4][128]
#define P_WF0    13312    // [128]
#define P_WF1    13440    // [128]
#define P_FB     13568    // [128]
#define P_CONDZ  13696    // [20][4][8]
#define P_SFC    14336    // [2][8]
#define P_RESB   14352    // [20][2]
#define P_SKIPB  14392    // [20][2]
#define P_ZB     14432    // [20][4]
#define P_LOGB   14512    // [4]
#define P_SKIPCB 14516    // [2]
#define P_Z0C    14520    // [4][6]
#define P_SKC    14544    // [2][3]
#define P_XS     14552    // [3][8]
#define P_SZ     14576    // [32]
#define P_SL     14608    // [32]
#define P_SKACC  14640    // [16]
#define P_R2     14656    // [16]
#define P_CF     14672    // [8][66]
#define P_PREVF  15200    // [8][132]
#define P_HF     16256    // [8][132]
#define P_RESF   17312    // [8][132]
#define P_RES0   18368    // [8][132]
#define POOL_FL  19456    // 77,824 bytes -> 2 blocks/CU (LDS-capacity pigeonhole)

// ---------------- coherent 16B exchange primitives ----------------
// L3S=true: sc0 sc1 (device/L3, cross-XCD safe). L3S=false: sc0 (XCD L2).
template<bool L3S> __device__ __forceinline__ f4 ldx(const f4* p) {
    f4 r;
    if constexpr (L3S)
        asm volatile("global_load_dwordx4 %0, %1, off sc0 sc1\n\ts_waitcnt vmcnt(0)"
                     : "=v"(r) : "v"(p) : "memory");
    else
        asm volatile("global_load_dwordx4 %0, %1, off sc0\n\ts_waitcnt vmcnt(0)"
                     : "=v"(r) : "v"(p) : "memory");
    return r;
}
template<bool L3S> __device__ __forceinline__ void ldx2(const f4* p0, const f4* p1, f4& a, f4& b) {
    if constexpr (L3S)
        asm volatile("global_load_dwordx4 %0, %2, off sc0 sc1\n\t"
                     "global_load_dwordx4 %1, %3, off sc0 sc1\n\t"
                     "s_waitcnt vmcnt(0)"
                     : "=&v"(a), "=&v"(b) : "v"(p0), "v"(p1) : "memory");
    else
        asm volatile("global_load_dwordx4 %0, %2, off sc0\n\t"
                     "global_load_dwordx4 %1, %3, off sc0\n\t"
                     "s_waitcnt vmcnt(0)"
                     : "=&v"(a), "=&v"(b) : "v"(p0), "v"(p1) : "memory");
}
template<bool L3S> __device__ __forceinline__ void ld4x(const f4* a0, const f4* a1, const f4* a2, const f4* a3,
                                                        f4& r0, f4& r1, f4& r2, f4& r3) {
    if constexpr (L3S)
        asm volatile("global_load_dwordx4 %0, %4, off sc0 sc1\n\t"
                     "global_load_dwordx4 %1, %5, off sc0 sc1\n\t"
                     "global_load_dwordx4 %2, %6, off sc0 sc1\n\t"
                     "global_load_dwordx4 %3, %7, off sc0 sc1\n\t"
                     "s_waitcnt vmcnt(0)"
                     : "=&v"(r0), "=&v"(r1), "=&v"(r2), "=&v"(r3)
                     : "v"(a0), "v"(a1), "v"(a2), "v"(a3) : "memory");
    else
        asm volatile("global_load_dwordx4 %0, %4, off sc0\n\t"
                     "global_load_dwordx4 %1, %5, off sc0\n\t"
                     "global_load_dwordx4 %2, %6, off sc0\n\t"
                     "global_load_dwordx4 %3, %7, off sc0\n\t"
                     "s_waitcnt vmcnt(0)"
                     : "=&v"(r0), "=&v"(r1), "=&v"(r2), "=&v"(r3)
                     : "v"(a0), "v"(a1), "v"(a2), "v"(a3) : "memory");
}
template<bool L3S> __device__ __forceinline__ void stx(f4* p, f4 v) {
    if constexpr (L3S)
        asm volatile("global_store_dwordx4 %0, %1, off sc0 sc1" :: "v"(p), "v"(v) : "memory");
    else
        asm volatile("global_store_dwordx4 %0, %1, off sc0" :: "v"(p), "v"(v) : "memory");
}
template<bool L3S> __device__ __forceinline__ void spin(const f4* p, int e, f4& a) {
    while (__float_as_int(a.w) != e) a = ldx<L3S>(p);
}

// ---------------- election word primitives ----------------
__device__ __forceinline__ u32 ldw_l3(const u32* p) {
    u32 r;
    asm volatile("global_load_dword %0, %1, off sc0 sc1\n\ts_waitcnt vmcnt(0)"
                 : "=v"(r) : "v"(p) : "memory");
    return r;
}
__device__ __forceinline__ void stw_l3(u32* p, u32 v) {
    asm volatile("global_store_dword %0, %1, off sc0 sc1\n\ts_waitcnt vmcnt(0)"
                 :: "v"(p), "v"(v) : "memory");
}
__device__ __forceinline__ u32 ldw_l2(const u32* p) {
    u32 r;
    asm volatile("global_load_dword %0, %1, off sc0\n\ts_waitcnt vmcnt(0)"
                 : "=v"(r) : "v"(p) : "memory");
    return r;
}
__device__ __forceinline__ void stw_l2(u32* p, u32 v) {
    asm volatile("global_store_dword %0, %1, off sc0\n\ts_waitcnt vmcnt(0)"
                 :: "v"(p), "v"(v) : "memory");
}
__device__ __forceinline__ ull rtime() {   // 100 MHz constant clock
    ull t;
    asm volatile("s_memrealtime %0\n\ts_waitcnt lgkmcnt(0)" : "=s"(t));
    return t;
}

// ---- payload packing (V = 3q+i): [0,8) -> sl[V]; [9,17) -> sl[V-1]; 8,17 pad
__device__ __forceinline__ float pick16(const float* sl, int V) {
    if (V < 8) return sl[V];
    if (V >= 9 && V < 17) return sl[V - 1];
    return 0.f;
}
template<bool L3S> __device__ __forceinline__ void publish16(f4* slot, int J, const float* sl, int e) {
    if (threadIdx.x < 6) {
        int q = threadIdx.x;
        f4 v;
        v.x = pick16(sl, 3*q);
        v.y = pick16(sl, 3*q + 1);
        v.z = pick16(sl, 3*q + 2);
        v.w = __int_as_float(e);
        stx<L3S>(slot + J*6 + q, v);
    }
}
template<bool L3S> __device__ __forceinline__ void publish_half(f4* slot, int J, int r, const float* half8,
                                                                int e, int m) {
    int base = 3*m;
    f4 v;
    v.x = half8[base];
    v.y = (base + 1 < 8) ? half8[base + 1] : 0.f;
    v.z = (base + 2 < 8) ? half8[base + 2] : 0.f;
    v.w = __int_as_float(e);
    stx<L3S>(slot + J*6 + 3*r + m, v);
}
__device__ __forceinline__ void scat16(float* dst, f4 v, int vi, bool dorelu) {
    int j = vi / 6, q = vi - 6*j;
    #pragma unroll
    for (int i = 0; i < 3; ++i) {
        int V = 3*q + i;
        float x = v[i];
        if (dorelu) x = fmaxf(x, 0.f);
        if (V < 8)                 dst[V*132 + 2*j]           = x;
        else if (V >= 9 && V < 17) dst[(V - 9)*132 + 2*j + 1] = x;
    }
}
template<bool L3S> __device__ __forceinline__ void consume16(const f4* slot, int e, float* dst, bool dorelu) {
    int m = threadIdx.x;
    const f4 *p0 = slot + m, *p1 = slot + 256 + m;
    f4 a, b;
    bool two = (m < 128);
    if (two) ldx2<L3S>(p0, p1, a, b); else a = ldx<L3S>(p0);
    spin<L3S>(p0, e, a);
    if (two) spin<L3S>(p1, e, b);
    scat16(dst, a, m, dorelu);
    if (two) scat16(dst, b, m + 256, dorelu);
}
template<bool L3S> __device__ __forceinline__ void consume_pair(const f4* sR, int eR, float* dR,
                                                                const f4* sH, int eH, float* dH) {
    int m = threadIdx.x;
    const f4 *pra = sR + m, *prb = sR + 256 + m, *pha = sH + m, *phb = sH + 256 + m;
    f4 ra, rb, ha, hb;
    bool two = (m < 128);
    if (two) ld4x<L3S>(pra, prb, pha, phb, ra, rb, ha, hb);
    else     ldx2<L3S>(pra, pha, ra, ha);
    spin<L3S>(pra, eR, ra);
    if (two) spin<L3S>(prb, eR, rb);
    scat16(dR, ra, m, false);
    if (two) scat16(dR, rb, m + 256, false);
    spin<L3S>(pha, eH, ha);
    if (two) spin<L3S>(phb, eH, hb);
    scat16(dH, ha, m, false);
    if (two) scat16(dH, hb, m + 256, false);
}

__device__ __forceinline__ int growf(int J, int g) {
    return (g < 2) ? (2*J + g) : (128 + 2*J + (g - 2));
}

// ============================================================
template<bool L3S>
__device__ __attribute__((noinline)) void wn_body(const int J,
    const float* __restrict__ enc,
    const float* __restrict__ first_w,  const float* __restrict__ first_b,
    const float* __restrict__ causal_w, const float* __restrict__ causal_b,
    const float* __restrict__ cond_w,   const float* __restrict__ cond_b,
    const float* __restrict__ res_w,    const float* __restrict__ res_b,
    const float* __restrict__ skip_w,   const float* __restrict__ skip_b,
    const float* __restrict__ skipc_w,  const float* __restrict__ skipc_b,
    const float* __restrict__ fc_w,     const float* __restrict__ fc_b,
    const float* __restrict__ condf_w,  const float* __restrict__ condf_b,
    const float* __restrict__ logits_w, const float* __restrict__ logits_b,
    float* __restrict__ wsf, float* __restrict__ out)
{
    extern __shared__ float pool[];
    const int tid = threadIdx.x;
    float* ring = wsf + OFF_RING;
    f4* xb = (f4*)(wsf + OFF_X);

    // ---------------- init: small LDS-resident params ----------------
    {
        int r = tid >> 7, i = tid & 127;
        pool[P_WSKIPC + tid] = skipc_w[(size_t)(2*J + r)*128 + i];
        pool[P_WFC + tid]    = fc_w[(size_t)(2*J + r)*128 + i];
    }
    for (int m = tid; m < 512; m += NTHR) {
        int w = m >> 7, i = m & 127;
        pool[P_WLOG + m] = logits_w[(size_t)(4*J + w)*128 + i];
    }
    if (tid < 128) {
        pool[P_WF0 + tid] = first_w[2*tid];
        pool[P_WF1 + tid] = first_w[2*tid + 1];
        pool[P_FB + tid]  = first_b[tid];
    }
    if (tid < 40) {
        int l = tid >> 1, r = tid & 1;
        pool[P_RESB + tid]  = res_b[l*128 + 2*J + r];
        pool[P_SKIPB + tid] = skip_b[l*128 + 2*J + r];
    }
    if (tid < 4) pool[P_LOGB + tid] = logits_b[4*J + tid];
    if (tid < 2) pool[P_SKIPCB + tid] = skipc_b[2*J + tid];
    if (tid < 8) {
        pool[P_XS + tid]      = 128.f/255.f - 0.5f;  // X(0)
        pool[P_XS + 8 + tid]  = 0.f;                 // X(-1)
        pool[P_XS + 16 + tid] = 0.f;                 // X(-2)
    }
    // stage causal slice 0 (for Z0C)
    {
        int g = tid >> 6, grow = growf(J, g);
        f4 w = *(const f4*)(causal_w + (size_t)grow*256 + (tid & 63)*4);
        *(f4*)&pool[P_WX + g*256 + (tid & 63)*4] = w;
    }
    __syncthreads();

    // layer-0 closed form: z0 = kf*KP + KC + x2*U + x1*C1 + x0*A0 + condz0
    if (tid < 4) {
        const float* ws_ = pool + P_WX + tid*256;   // [2j+k]
        float kp = 0.f, kc = 0.f, u = 0.f, c1 = 0.f, a0 = 0.f;
        for (int j = 0; j < 128; ++j) {
            float w0 = ws_[2*j], w1 = ws_[2*j + 1];
            float f0 = pool[P_WF0 + j], f1 = pool[P_WF1 + j], fbv = pool[P_FB + j];
            kp += w0*fbv; kc += w1*fbv;
            u  += w0*f0;  c1 += w0*f1 + w1*f0;  a0 += w1*f1;
        }
        pool[P_Z0C + tid*6 + 0] = kp;
        pool[P_Z0C + tid*6 + 1] = kc;
        pool[P_Z0C + tid*6 + 2] = u;
        pool[P_Z0C + tid*6 + 3] = c1;
        pool[P_Z0C + tid*6 + 4] = a0;
        pool[P_ZB + tid] = 0.f;   // zb_0 = 0
    }
    // skip-init closed form: skip0 = SK + x1*SA + x0*SB
    if (tid < 2) {
        const float* wr = pool + P_WSKIPC + tid*128;
        float sk = pool[P_SKIPCB + tid], sa = 0.f, sb = 0.f;
        for (int j = 0; j < 128; ++j) {
            sk += wr[j]*pool[P_FB + j];
            sa += wr[j]*pool[P_WF0 + j];
            sb += wr[j]*pool[P_WF1 + j];
        }
        pool[P_SKC + tid*3 + 0] = sk;
        pool[P_SKC + tid*3 + 1] = sa;
        pool[P_SKC + tid*3 + 2] = sb;
    }
    __syncthreads();

    // F_l[g][j] = sum_i W1_{l+1}[g][i] * res_w[l][i][j]; zb_{l+1}[g] = W1_{l+1}[g].res_b[l]
    for (int l = 0; l < 19; ++l) {
        {
            int g = tid >> 6, grow = growf(J, g);
            f4 w = *(const f4*)(causal_w + ((size_t)((l+1)*256 + grow))*256 + (tid & 63)*4);
            *(f4*)&pool[P_WX + g*256 + (tid & 63)*4] = w;
        }
        __syncthreads();
        for (int m = tid; m < 512; m += NTHR) {
            int g = m >> 7, j = m & 127;
            const float* w1 = pool + P_WX + g*256;
            const float* rw = res_w + (size_t)l*128*128 + j;
            float acc = 0.f;
            #pragma unroll 8
            for (int i = 0; i < 128; ++i) acc += w1[2*i + 1] * rw[(size_t)i*128];
            pool[P_F + (l*4 + g)*128 + j] = acc;
        }
        if (tid < 4) {
            const float* w1 = pool + P_WX + tid*256;
            float acc = 0.f;
            for (int i = 0; i < 128; ++i) acc += w1[2*i + 1] * res_b[l*128 + i];
            pool[P_ZB + (l+1)*4 + tid] = acc;
        }
        __syncthreads();
    }

    int e = 0;            // exchange epoch
    int er_pending = 0;   // epoch of most recent res publish
    int esk = 0;          // epoch of skip publish

    for (int t = 0; t < TT; ++t) {
        // ---------------- per-chunk precompute ----------------
        if ((t & 63) == 0) {
            int te = t >> 6;
            for (int m = tid; m < 512; m += NTHR) {
                int b = m >> 6, j = m & 63;
                pool[P_CF + b*66 + j] = enc[(size_t)b*512 + j*8 + te];
            }
            __syncthreads();
            for (int m = tid; m < 640; m += NTHR) {
                int l = m >> 5, rem = m & 31, g = rem >> 3, b = rem & 7;
                int grow = growf(J, g);
                float acc = causal_b[l*256 + grow] + cond_b[l*256 + grow]
                          + pool[P_ZB + l*4 + g];
                const float* cw = cond_w + (size_t)(l*256 + grow)*64;
                const float* cf = pool + P_CF + b*66;
                for (int j = 0; j < 64; ++j) acc += cw[j]*cf[j];
                pool[P_CONDZ + l*32 + g*8 + b] = acc;
            }
            if (tid < 16) {
                int r = tid >> 3, b = tid & 7, row = 2*J + r;
                float acc = fc_b[row] + condf_b[row];
                const float* cw = condf_w + (size_t)row*64;
                const float* cf = pool + P_CF + b*66;
                for (int j = 0; j < 64; ++j) acc += cw[j]*cf[j];
                pool[P_SFC + r*8 + b] = acc;
            }
            __syncthreads();
        }

        // ---------------- h_0 closed form + immediate publish ----------------
        ++e; const int eh0 = e;
        {
            if (tid < 16) {
                int r = tid & 1, b = tid >> 1;
                float kf  = (t >= 1) ? 1.f : 0.f;
                float x0v = pool[P_XS + b];
                float x1v = pool[P_XS + 8 + b];
                float x2v = pool[P_XS + 16 + b];
                const float* zc = pool + P_Z0C;
                int g0 = r, g1 = 2 + r;
                float zg = kf*zc[g0*6+0] + zc[g0*6+1] + x2v*zc[g0*6+2]
                         + x1v*zc[g0*6+3] + x0v*zc[g0*6+4] + pool[P_CONDZ + g0*8 + b];
                float zo = kf*zc[g1*6+0] + zc[g1*6+1] + x2v*zc[g1*6+2]
                         + x1v*zc[g1*6+3] + x0v*zc[g1*6+4] + pool[P_CONDZ + g1*8 + b];
                pool[P_SL + r*8 + b] = (1.f/(1.f + expf(-zg))) * tanhf(zo);
            }
            publish16<L3S>(xb + (size_t)(eh0 & 3)*768, J, pool + P_SL, eh0);
        }
        // res_0 full (overlaps h_0 RTT)
        for (int m = tid; m < 1024; m += NTHR) {
            int b = m >> 7, r = m & 127;
            pool[P_RES0 + b*132 + r] =
                pool[P_FB + r] + pool[P_XS + 8 + b]*pool[P_WF0 + r]
                               + pool[P_XS + b]    *pool[P_WF1 + r];
        }
        // skip init + r2 init (closed form)
        if (tid < 16) {
            int r = tid >> 3, b = tid & 7;
            float x0v = pool[P_XS + b], x1v = pool[P_XS + 8 + b];
            pool[P_SKACC + r*8 + b] = pool[P_SKC + r*3] + x1v*pool[P_SKC + r*3 + 1]
                                                        + x0v*pool[P_SKC + r*3 + 2];
            int row = 2*J + r;
            pool[P_R2 + r*8 + b] = pool[P_FB + row] + x1v*pool[P_WF0 + row]
                                                    + x0v*pool[P_WF1 + row];
        }

        // ---------------- layer loop ----------------
        for (int l = 0; l < LL; ++l) {
            int ehh;
            if (l == 0) {
                ehh = eh0;
            } else {
                // S1: z_l = W0.prev + W1.res_{l-1} + F_{l-1}.h_{l-1} + condz
                {
                    int g = tid >> 6, lane = tid & 63, b = lane >> 3, k = lane & 7;
                    const float* wz = pool + P_WX + (l & 1)*1024 + g*256;  // [2j+k]
                    const float* pv = pool + P_PREVF + b*132;
                    const float* rs = ((l == 1) ? pool + P_RES0 : pool + P_RESF) + b*132;
                    const float* fm = pool + P_F + ((l-1)*4 + g)*128;
                    const float* hh = pool + P_HF + b*132;
                    float acc = 0.f;
                    #pragma unroll
                    for (int i = 0; i < 16; ++i) {
                        int j = k + 8*i;
                        acc += wz[2*j]*pv[j] + wz[2*j + 1]*rs[j] + fm[j]*hh[j];
                    }
                    acc += __shfl_xor(acc,1); acc += __shfl_xor(acc,2); acc += __shfl_xor(acc,4);
                    if (k == 0) pool[P_SZ + g*8 + b] = acc;
                }
                __syncthreads();
                // S3 + publish (wave 0, same-wave LDS ordering)
                ++e; ehh = e;
                if (tid < 16) {
                    int r = tid & 1, b = tid >> 1;
                    float g = pool[P_SZ + r*8 + b]     + pool[P_CONDZ + l*32 + r*8 + b];
                    float o = pool[P_SZ + (2+r)*8 + b] + pool[P_CONDZ + l*32 + (2+r)*8 + b];
                    pool[P_SL + r*8 + b] = (1.f/(1.f + expf(-g))) * tanhf(o);
                }
                publish16<L3S>(xb + (size_t)(ehh & 3)*768, J, pool + P_SL, ehh);
            }
            // S6: stage this layer's res/skip rows + NEXT layer's causal slice
            float wv0, wv1;
            {
                int r0 = tid >> 7, i0 = tid & 127;
                wv0 = res_w [(size_t)(l*128 + 2*J + r0)*128 + i0];
                wv1 = skip_w[(size_t)(l*128 + 2*J + r0)*128 + i0];
            }
            f4 wcx;
            if (l <= 18) {
                int g = tid >> 6, grow = growf(J, g);
                wcx = *(const f4*)(causal_w + ((size_t)((l+1)*256 + grow))*256 + (tid & 63)*4);
            }
            // S7: ring prefetch prev_{l+1}
            ull pfa = 0, pfb = 0;
            if (l <= 18) {
                int d = c_dil[l+1];
                if (t >= d) {
                    int slot = (t - d) & (2*d - 1);
                    const float* rp = ring + c_roff[l+1] + (size_t)slot*1024 + tid*4;
                    pfa = __hip_atomic_load((const ull*)rp,     __ATOMIC_RELAXED, __HIP_MEMORY_SCOPE_AGENT);
                    pfb = __hip_atomic_load((const ull*)(rp+2), __ATOMIC_RELAXED, __HIP_MEMORY_SCOPE_AGENT);
                }
            }
            // S7.5/S8: consume res_l (layer-old) + h_l (fused issue)
            if (l == 0) {
                consume16<L3S>(xb + (size_t)(ehh & 3)*768, ehh, pool + P_HF, false);
            } else if (l <= 18) {
                consume_pair<L3S>(xb + (size_t)(er_pending & 3)*768, er_pending, pool + P_RESF,
                                  xb + (size_t)(ehh & 3)*768,        ehh,        pool + P_HF);
            } else {
                consume16<L3S>(xb + (size_t)(ehh & 3)*768, ehh, pool + P_HF, false);
            }
            // S8.5: land staged weight rows
            pool[P_WST + tid] = wv0;
            pool[P_WST + 256 + tid] = wv1;
            __syncthreads();   // bar A
            // S10: dres slice (waves 0,1) + skip accum (waves 2,3)
            {
                int w = tid >> 6, lane = tid & 63, b = lane >> 3, k = lane & 7;
                int r = w & 1, isSkip = w >> 1;
                if (isSkip || l <= 18) {
                    const float* wr = pool + P_WST + (isSkip ? 256 : 0) + r*128;
                    const float* hh = pool + P_HF + b*132;
                    float acc = 0.f;
                    #pragma unroll
                    for (int i = 0; i < 16; ++i) { int j = k + 8*i; acc += wr[j]*hh[j]; }
                    acc += __shfl_xor(acc,1); acc += __shfl_xor(acc,2); acc += __shfl_xor(acc,4);
                    if (k == 0) {
                        if (isSkip) {
                            pool[P_SKACC + r*8 + b] += acc + pool[P_SKIPB + l*2 + r];
                        } else {
                            float v = pool[P_R2 + r*8 + b] + acc + pool[P_RESB + l*2 + r];
                            pool[P_R2 + r*8 + b] = v;
                            pool[P_SL + r*8 + b] = v;
                            int d = c_dil[l+1];
                            int slot = t & (2*d - 1);
                            float* wp = ring + c_roff[l+1] + (size_t)slot*1024 + b*128 + 2*J + r;
                            __hip_atomic_store(wp, v, __ATOMIC_RELAXED, __HIP_MEMORY_SCOPE_AGENT);
                        }
                    }
                }
            }
            // S10b: in-wave publishes
            {
                int w = tid >> 6, lane = tid & 63;
                if (l <= 17) {
                    ++e; er_pending = e;
                    if (w < 2 && lane < 3)
                        publish_half<L3S>(xb + (size_t)(e & 3)*768, J, w,
                                          pool + P_SL + w*8, e, lane);
                } else if (l == 19) {
                    ++e; esk = e;
                    if (w >= 2 && lane < 3)
                        publish_half<L3S>(xb + (size_t)(e & 3)*768, J, w - 2,
                                          pool + P_SKACC + (w - 2)*8, e, lane);
                }
            }
            // S11: land prev prefetch + land next causal slice
            if (l <= 18) {
                int b = tid >> 5, c = (tid & 31)*4;
                union { ull u; float f[2]; } u0, u1;
                u0.u = pfa; u1.u = pfb;
                float* dp = pool + P_PREVF + b*132 + c;
                dp[0] = u0.f[0]; dp[1] = u0.f[1]; dp[2] = u1.f[0]; dp[3] = u1.f[1];
                *(f4*)&pool[P_WX + ((l+1) & 1)*1024 + (tid >> 6)*256 + (tid & 63)*4] = wcx;
            }
            __syncthreads();   // bar B
        }

        // ---------------- head ----------------
        consume16<L3S>(xb + (size_t)(esk & 3)*768, esk, pool + P_HF, false);   // skip gather
        __syncthreads();
        {
            int w = tid >> 6, lane = tid & 63, b = lane >> 3, k = lane & 7;
            if (w < 2) {
                const float* wr = pool + P_WFC + w*128;
                const float* sk = pool + P_HF + b*132;
                float acc = 0.f;
                #pragma unroll
                for (int i = 0; i < 16; ++i) { int j = k + 8*i; acc += wr[j]*fmaxf(sk[j], 0.f); }
                acc += __shfl_xor(acc,1); acc += __shfl_xor(acc,2); acc += __shfl_xor(acc,4);
                if (k == 0) pool[P_SL + w*8 + b] = acc + pool[P_SFC + w*8 + b];
            }
        }
        ++e;
        {
            int w = tid >> 6, lane = tid & 63;
            if (w < 2 && lane < 3)
                publish_half<L3S>(xb + (size_t)(e & 3)*768, J, w, pool + P_SL + w*8, e, lane);
        }
        consume16<L3S>(xb + (size_t)(e & 3)*768, e, pool + P_RESF, true);   // relu(s) gather
        __syncthreads();
        // logits rows + direct out-store + block-local argmax pair
        {
            int b = tid >> 5, g = (tid >> 3) & 3, k = tid & 7;
            const float* wr = pool + P_WLOG + g*128;
            const float* sv = pool + P_RESF + b*132;
            float acc = 0.f;
            #pragma unroll
            for (int i = 0; i < 16; ++i) { int j = k + 8*i; acc += wr[j]*sv[j]; }
            acc += __shfl_xor(acc,1); acc += __shfl_xor(acc,2); acc += __shfl_xor(acc,4);
            float v = acc + pool[P_LOGB + g];
            float best = (k == 0) ? v : -3.4e38f;
            int bi = 4*J + g;
            { float ov = __shfl_xor(best, 8);  int oi = __shfl_xor(bi, 8);
              if (ov > best || (ov == best && oi < bi)) { best = ov; bi = oi; } }
            { float ov = __shfl_xor(best, 16); int oi = __shfl_xor(bi, 16);
              if (ov > best || (ov == best && oi < bi)) { best = ov; bi = oi; } }
            if (k == 0) out[4096 + ((size_t)(t*BB + b))*256 + 4*J + g] = v;
            if ((tid & 31) == 0) { pool[P_SL + b] = best; pool[P_SL + 8 + b] = (float)bi; }
        }
        __syncthreads();
        ++e;
        publish16<L3S>(xb + (size_t)(e & 3)*768, J, pool + P_SL, e);   // 64 (max,idx) pairs
        consume16<L3S>(xb + (size_t)(e & 3)*768, e, pool + P_HF, false);
        __syncthreads();
        // final argmax reduce + x shift
        if (tid < 64) {
            int b = tid >> 3, j0 = tid & 7;
            float best = -3.4e38f; float bidx = 0.f;
            #pragma unroll
            for (int k2 = 0; k2 < 8; ++k2) {
                int j = j0*8 + k2;
                float v  = pool[P_HF + b*132 + 2*j];
                float id = pool[P_HF + b*132 + 2*j + 1];
                if (v > best || (v == best && id < bidx)) { best = v; bidx = id; }
            }
            #pragma unroll
            for (int m = 4; m >= 1; m >>= 1) {
                float ov = __shfl_xor(best, m); float oi = __shfl_xor(bidx, m);
                if (ov > best || (ov == best && oi < bidx)) { best = ov; bidx = oi; }
            }
            if (j0 == 0) {
                if (J == 0) out[t*BB + b] = bidx;
                pool[P_XS + 16 + b] = pool[P_XS + 8 + b];
                pool[P_XS + 8 + b]  = pool[P_XS + b];
                pool[P_XS + b]      = bidx*(1.f/255.f) - 0.5f;
            }
        }
        __syncthreads();
    }
}

// ============================================================
__global__ __launch_bounds__(NTHR, 1) void wn_gen(
    const float* __restrict__ enc,
    const float* __restrict__ first_w,  const float* __restrict__ first_b,
    const float* __restrict__ causal_w, const float* __restrict__ causal_b,
    const float* __restrict__ cond_w,   const float* __restrict__ cond_b,
    const float* __restrict__ res_w,    const float* __restrict__ res_b,
    const float* __restrict__ skip_w,   const float* __restrict__ skip_b,
    const float* __restrict__ skipc_w,  const float* __restrict__ skipc_b,
    const float* __restrict__ fc_w,     const float* __restrict__ fc_b,
    const float* __restrict__ condf_w,  const float* __restrict__ condf_b,
    const float* __restrict__ logits_w, const float* __restrict__ logits_b,
    float* __restrict__ wsf, float* __restrict__ out)
{
    extern __shared__ float pool[];
    int* ip = (int*)pool;
    const int tid = threadIdx.x;
    // election cells overlay mailbox slot 0: [0..63] PRES1, [64..127] TEST,
    // [128..191] PRES2, [192] V1, [193] V2  (all hash-tagged per launch)
    u32* ex = (u32*)(wsf + OFF_X);

    unsigned int xcc;
    asm volatile("s_getreg_b32 %0, hwreg(HW_REG_XCC_ID)" : "=s"(xcc));
    xcc &= 15u;

    if (tid == 0) {
        ull tk = atomicAdd(&g_seq, 1ull);
        u32 tag = (u32)(tk >> 9) + 1u;         // fresh per launch (512 blocks)
        u32 idx = (u32)(tk & 511ull);          // global arrival order
        // per-XCD tagged rank (CAS loop)
        u32 rk;
        {
            u32* cp = &g_xcnt[xcc];
            u32 old = __hip_atomic_load(cp, __ATOMIC_RELAXED, __HIP_MEMORY_SCOPE_AGENT);
            while (true) {
                u32 nv, mr;
                if ((old >> 10) == tag) { mr = old & 1023u; nv = old + 1u; }
                else                    { mr = 0u; nv = (tag << 10) | 1u; }
                u32 prev = atomicCAS(cp, old, nv);
                if (prev == old) { rk = mr; break; }
                old = prev;
            }
        }
        ip[0] = (int)tag; ip[1] = (int)idx; ip[2] = (int)rk;
    }
    __syncthreads();
    const u32 tag = (u32)ip[0];
    const u32 idx = (u32)ip[1];
    const u32 rnk = (u32)ip[2];
    const u32 hsh = tag * 0x9E3779B1u;
    const bool primary = (xcc == 0u && rnk < (u32)WK);
    const bool reserve = (idx < (u32)WK);

    if (tid == 0) {
        if (primary) stw_l3(ex + rnk, hsh);
        if (idx == 0u) {
            // bounded collect of primary presence (2 ms)
            ull t0 = rtime(); int done = 0;
            while (!done) {
                int c = 0;
                for (int j = 0; j < WK; ++j) c += (ldw_l3(ex + j) == hsh) ? 1 : 0;
                done = (c == WK);
                if (!done && (rtime() - t0) > 200000ull) break;
            }
            stw_l3(ex + 192, (hsh & ~3u) | (done ? 1u : 2u));
        }
        // bounded verdict poll (50 ms; decider publishes within ~2 ms)
        u32 verd = 2u;
        ull t1 = rtime();
        while (true) {
            u32 v = ldw_l3(ex + 192);
            if ((v & ~3u) == (hsh & ~3u)) { verd = v & 3u; break; }
            if ((rtime() - t1) > 5000000ull) break;
        }
        ip[3] = (int)verd;
    }
    __syncthreads();
    const u32 verd = (u32)ip[3];

    if (verd == 1u) {
        if (!primary) return;
        const int J = (int)rnk;
        if (tid == 0) {
            // XCD-L2 coherence self-test: all-to-all sc0 visibility (bounded)
            stw_l2(ex + 64 + J, hsh);
            ull t0 = rtime(); int ok = 0;
            while (!ok) {
                int c = 0;
                for (int j = 0; j < WK; ++j) c += (ldw_l2(ex + 64 + j) == hsh) ? 1 : 0;
                ok = (c == WK);
                if (!ok && (rtime() - t0) > 200000ull) break;
            }
            stw_l3(ex + 128 + J, (hsh & ~1u) | (ok ? 1u : 0u));
            if (J == 0) {
                ull t1 = rtime(); int allok = 0;
                while (!allok) {
                    int c = 0;
                    for (int j = 0; j < WK; ++j)
                        c += (ldw_l3(ex + 128 + j) == ((hsh & ~1u) | 1u)) ? 1 : 0;
                    allok = (c == WK);
                    if (!allok && (rtime() - t1) > 400000ull) break;
                }
                stw_l3(ex + 193, (hsh & ~3u) | (allok ? 1u : 2u));
            }
            u32 fin = 2u;
            ull t2 = rtime();
            while (true) {
                u32 v = ldw_l3(ex + 193);
                if ((v & ~3u) == (hsh & ~3u)) { fin = v & 3u; break; }
                if ((rtime() - t2) > 5000000ull) break;
            }
            ip[4] = (int)fin;
        }
        __syncthreads();
        if (ip[4] == 1)
            wn_body<false>(J, enc, first_w, first_b, causal_w, causal_b, cond_w, cond_b,
                           res_w, res_b, skip_w, skip_b, skipc_w, skipc_b, fc_w, fc_b,
                           condf_w, condf_b, logits_w, logits_b, wsf, out);
        else
            wn_body<true>(J, enc, first_w, first_b, causal_w, causal_b, cond_w, cond_b,
                          res_w, res_b, skip_w, skip_b, skipc_w, skipc_b, fc_w, fc_b,
                          condf_w, condf_b, logits_w, logits_b, wsf, out);
    } else {
        if (!reserve) return;
        wn_body<true>((int)idx, enc, first_w, first_b, causal_w, causal_b, cond_w, cond_b,
                      res_w, res_b, skip_w, skip_b, skipc_w, skipc_b, fc_w, fc_b,
                      condf_w, condf_b, logits_w, logits_b, wsf, out);
    }
}

// ============================================================
extern "C" void kernel_launch(void* const* d_in, const int* in_sizes, int n_in,
                              void* d_out, int out_size, void* d_ws, size_t ws_size,
                              hipStream_t stream) {
    const float* enc      = (const float*)d_in[0];
    const float* first_w  = (const float*)d_in[1];
    const float* first_b  = (const float*)d_in[2];
    const float* causal_w = (const float*)d_in[3];
    const float* causal_b = (const float*)d_in[4];
    const float* cond_w   = (const float*)d_in[5];
    const float* cond_b   = (const float*)d_in[6];
    const float* res_w    = (const float*)d_in[7];
    const float* res_b    = (const float*)d_in[8];
    const float* skip_w   = (const float*)d_in[9];
    const float* skip_b   = (const float*)d_in[10];
    const float* skipc_w  = (const float*)d_in[11];
    const float* skipc_b  = (const float*)d_in[12];
    const float* fc_w     = (const float*)d_in[13];
    const float* fc_b     = (const float*)d_in[14];
    const float* condf_w  = (const float*)d_in[15];
    const float* condf_b  = (const float*)d_in[16];
    const float* logits_w = (const float*)d_in[17];
    const float* logits_b = (const float*)d_in[18];

    float* wsf = (float*)d_ws;
    float* out = (float*)d_out;

    wn_gen<<<GRID, NTHR, POOL_FL*4, stream>>>(
        enc, first_w, first_b, causal_w, causal_b, cond_w, cond_b,
        res_w, res_b, skip_w, skip_b, skipc_w, skipc_b, fc_w, fc_b,
        condf_w, condf_b, logits_w, logits_b, wsf, out);
}

// Round 5
// 36855.701 us; speedup vs baseline: 1.1880x; 1.1880x over previous
//
#include <hip/hip_runtime.h>
#include <math.h>

// ---------------- problem constants ----------------
#define BB 8
#define TT 512
#define LL 20
#define NBLK 64
#define NTHR 256

typedef float f4 __attribute__((ext_vector_type(4)));
typedef unsigned long long ull;

__constant__ int c_dil[LL] = {1,2,4,8,16,32,64,128,256,512,
                              1,2,4,8,16,32,64,128,256,512};
// double-buffered rings: layer l has 2*d slots of 1024 floats (ring[0] unused)
__constant__ int c_roff[LL] = {-1,0,4096,12288,28672,61440,126976,258048,520192,1044480,
                               2093056,2095104,2099200,2107392,2123776,2156544,
                               2222080,2353152,2615296,3139584};

// ---------------- workspace layout (floats) ----------------
constexpr size_t OFF_RING = 0;          // 4,188,160 floats
constexpr size_t OFF_X    = 4188160;    // exchange: 4 slots * 768 float4

// ---------------- LDS pool offsets (floats) ----------------
#define P_WC     0        // [20][4][256]: z-row g: [0:128]=W0(prev) [128:256]=W1(res)
#define P_F      20480    // [19][4][128]: F_l = W1_{l+1}slice . Wres_l^T
#define P_WST    30208    // [512]: per-layer staged res/skip rows
#define P_WSKIPC 30720    // [2][128]
#define P_WFC    30976    // [2][128]
#define P_WLOG   31232    // [4][128]
#define P_WF0    31744    // [128]
#define P_WF1    31872    // [128]
#define P_FB     32000    // [128]
#define P_CONDZ  32128    // [20][4][8]  (includes zb fold)
#define P_SFC    32768    // [2][8]
#define P_RESB   32784    // [20][2]
#define P_SKIPB  32824    // [20][2]
#define P_ZB     32864    // [20][4]
#define P_LOGB   32944    // [4]
#define P_SKIPCB 32948    // [2]
#define P_Z0C    32952    // [4][6]
#define P_SKC    32976    // [2][3]
#define P_XS     32984    // [3][8]
#define P_SL     33008    // [32]
#define P_SKACC  33040    // [16]
#define P_R2     33056    // [16]
#define P_CF     33072    // [8][66]
#define P_PREVF  33600    // [8][132]
#define P_HF     34656    // [2][8][132] parity buffers
#define P_RESF   36768    // [2][8][132] parity buffers (buf0 also holds res_0)
#define POOL_FL  38880    // 155,520 bytes -> 1 block/CU

// ---------------- coherent 16B exchange primitives (sc0 sc1 -> L3) ----------
__device__ __forceinline__ f4 ldx(const f4* p) {
    f4 r;
    asm volatile("global_load_dwordx4 %0, %1, off sc0 sc1\n\ts_waitcnt vmcnt(0)"
                 : "=v"(r) : "v"(p) : "memory");
    return r;
}
__device__ __forceinline__ void ldx2(const f4* p0, const f4* p1, f4& a, f4& b) {
    asm volatile("global_load_dwordx4 %0, %2, off sc0 sc1\n\t"
                 "global_load_dwordx4 %1, %3, off sc0 sc1\n\t"
                 "s_waitcnt vmcnt(0)"
                 : "=&v"(a), "=&v"(b) : "v"(p0), "v"(p1) : "memory");
}
__device__ __forceinline__ void ld4x(const f4* a0, const f4* a1, const f4* a2, const f4* a3,
                                     f4& r0, f4& r1, f4& r2, f4& r3) {
    asm volatile("global_load_dwordx4 %0, %4, off sc0 sc1\n\t"
                 "global_load_dwordx4 %1, %5, off sc0 sc1\n\t"
                 "global_load_dwordx4 %2, %6, off sc0 sc1\n\t"
                 "global_load_dwordx4 %3, %7, off sc0 sc1\n\t"
                 "s_waitcnt vmcnt(0)"
                 : "=&v"(r0), "=&v"(r1), "=&v"(r2), "=&v"(r3)
                 : "v"(a0), "v"(a1), "v"(a2), "v"(a3) : "memory");
}
__device__ __forceinline__ void stx(f4* p, f4 v) {
    asm volatile("global_store_dwordx4 %0, %1, off sc0 sc1"
                 :: "v"(p), "v"(v) : "memory");
}
__device__ __forceinline__ void spin(const f4* p, int e, f4& a) {
    while (__float_as_int(a.w) != e) a = ldx(p);
}

// ---- payload packing (V = 3q+i): [0,8) -> sl[V]; [9,17) -> sl[V-1]; 8,17 pad
__device__ __forceinline__ float pick16(const float* sl, int V) {
    if (V < 8) return sl[V];
    if (V >= 9 && V < 17) return sl[V - 1];
    return 0.f;
}
__device__ __forceinline__ void publish16(f4* slot, int J, const float* sl, int e) {
    if (threadIdx.x < 6) {
        int q = threadIdx.x;
        f4 v;
        v.x = pick16(sl, 3*q);
        v.y = pick16(sl, 3*q + 1);
        v.z = pick16(sl, 3*q + 2);
        v.w = __int_as_float(e);
        stx(slot + J*6 + q, v);
    }
}
// half-publish: wave holding half r (8 floats) publishes its own 3 f4 (lanes m=0..2)
__device__ __forceinline__ void publish_half(f4* slot, int J, int r, const float* half8,
                                             int e, int m) {
    int base = 3*m;
    f4 v;
    v.x = half8[base];
    v.y = (base + 1 < 8) ? half8[base + 1] : 0.f;
    v.z = (base + 2 < 8) ? half8[base + 2] : 0.f;
    v.w = __int_as_float(e);
    stx(slot + J*6 + 3*r + m, v);
}
__device__ __forceinline__ void scat16(float* dst, f4 v, int vi, bool dorelu) {
    int j = vi / 6, q = vi - 6*j;
    #pragma unroll
    for (int i = 0; i < 3; ++i) {
        int V = 3*q + i;
        float x = v[i];
        if (dorelu) x = fmaxf(x, 0.f);
        if (V < 8)                 dst[V*132 + 2*j]           = x;
        else if (V >= 9 && V < 17) dst[(V - 9)*132 + 2*j + 1] = x;
    }
}
__device__ __forceinline__ void consume16(const f4* slot, int e, float* dst, bool dorelu) {
    int m = threadIdx.x;
    const f4 *p0 = slot + m, *p1 = slot + 256 + m;
    f4 a, b;
    bool two = (m < 128);
    if (two) ldx2(p0, p1, a, b); else a = ldx(p0);
    spin(p0, e, a);
    if (two) spin(p1, e, b);
    scat16(dst, a, m, dorelu);
    if (two) scat16(dst, b, m + 256, dorelu);
}
// fused: res (published a layer ago) + h (published this layer) — one vmcnt(0) issue
__device__ __forceinline__ void consume_pair(const f4* sR, int eR, float* dR,
                                             const f4* sH, int eH, float* dH) {
    int m = threadIdx.x;
    const f4 *pra = sR + m, *prb = sR + 256 + m, *pha = sH + m, *phb = sH + 256 + m;
    f4 ra, rb, ha, hb;
    bool two = (m < 128);
    if (two) ld4x(pra, prb, pha, phb, ra, rb, ha, hb);
    else     ldx2(pra, pha, ra, ha);
    spin(pra, eR, ra);
    if (two) spin(prb, eR, rb);
    scat16(dR, ra, m, false);
    if (two) scat16(dR, rb, m + 256, false);
    spin(pha, eH, ha);
    if (two) spin(phb, eH, hb);
    scat16(dH, ha, m, false);
    if (two) scat16(dH, hb, m + 256, false);
}

__device__ __forceinline__ float dotf4(f4 a, f4 b) {
    return a.x*b.x + a.y*b.y + a.z*b.z + a.w*b.w;
}

// ============================================================
__global__ __launch_bounds__(NTHR, 1) void wn_gen(
    const float* __restrict__ enc,
    const float* __restrict__ first_w,  const float* __restrict__ first_b,
    const float* __restrict__ causal_w, const float* __restrict__ causal_b,
    const float* __restrict__ cond_w,   const float* __restrict__ cond_b,
    const float* __restrict__ res_w,    const float* __restrict__ res_b,
    const float* __restrict__ skip_w,   const float* __restrict__ skip_b,
    const float* __restrict__ skipc_w,  const float* __restrict__ skipc_b,
    const float* __restrict__ fc_w,     const float* __restrict__ fc_b,
    const float* __restrict__ condf_w,  const float* __restrict__ condf_b,
    const float* __restrict__ logits_w, const float* __restrict__ logits_b,
    float* __restrict__ wsf, float* __restrict__ out)
{
    extern __shared__ float pool[];
    const int tid = threadIdx.x;
    const int J = blockIdx.x;
    float* ring = wsf + OFF_RING;
    f4* xb = (f4*)(wsf + OFF_X);

    // ---------------- init: weight slices -> LDS ----------------
    for (int m = tid; m < 20480; m += NTHR) {
        int l = m >> 10, rem = m & 1023, g = rem >> 8, i = rem & 255;
        int grow = (g < 2) ? (2*J + g) : (128 + 2*J + (g - 2));
        int col = i & 127, k = i >> 7;
        pool[P_WC + m] = causal_w[((size_t)(l*256 + grow)*128 + col)*2 + k];
    }
    if (tid < 256) {
        int r = tid >> 7, i = tid & 127;
        pool[P_WSKIPC + tid] = skipc_w[(size_t)(2*J + r)*128 + i];
        pool[P_WFC + tid]    = fc_w[(size_t)(2*J + r)*128 + i];
    }
    for (int m = tid; m < 512; m += NTHR) {
        int w = m >> 7, i = m & 127;
        pool[P_WLOG + m] = logits_w[(size_t)(4*J + w)*128 + i];
    }
    if (tid < 128) {
        pool[P_WF0 + tid] = first_w[2*tid];
        pool[P_WF1 + tid] = first_w[2*tid + 1];
        pool[P_FB + tid]  = first_b[tid];
    }
    if (tid < 40) {
        int l = tid >> 1, r = tid & 1;
        pool[P_RESB + tid]  = res_b[l*128 + 2*J + r];
        pool[P_SKIPB + tid] = skip_b[l*128 + 2*J + r];
    }
    if (tid < 4) pool[P_LOGB + tid] = logits_b[4*J + tid];
    if (tid < 2) pool[P_SKIPCB + tid] = skipc_b[2*J + tid];
    if (tid < 8) {
        pool[P_XS + tid]      = 128.f/255.f - 0.5f;  // X(0)
        pool[P_XS + 8 + tid]  = 0.f;                 // X(-1)
        pool[P_XS + 16 + tid] = 0.f;                 // X(-2)
    }
    __syncthreads();   // P_WC / first-layer params ready

    // F_l[g][j] = sum_i W1_{l+1}[g][i] * res_w[l][i][j]   (l = 0..18)
    for (int l = 0; l < 19; ++l) {
        for (int m = tid; m < 512; m += NTHR) {
            int g = m >> 7, j = m & 127;
            const float* w1 = pool + P_WC + ((l+1)*4 + g)*256 + 128;
            const float* rw = res_w + (size_t)l*128*128 + j;
            float acc = 0.f;
            #pragma unroll 8
            for (int i = 0; i < 128; ++i) acc += w1[i] * rw[(size_t)i*128];
            pool[P_F + (l*4 + g)*128 + j] = acc;
        }
    }
    // zb_l[g] = W1_l[g] . res_b[l-1]  (l >= 1)
    if (tid < 80) {
        int l = tid >> 2, g = tid & 3;
        float acc = 0.f;
        if (l >= 1) {
            const float* w1 = pool + P_WC + (l*4 + g)*256 + 128;
            for (int i = 0; i < 128; ++i) acc += w1[i] * res_b[(l-1)*128 + i];
        }
        pool[P_ZB + tid] = acc;
    }
    // layer-0 closed form: z0 = kf*KP + KC + x2*U + x1*C1 + x0*A0 + condz0
    if (tid < 4) {
        const float* w0 = pool + P_WC + tid*256;
        const float* w1 = w0 + 128;
        float kp = 0.f, kc = 0.f, u = 0.f, c1 = 0.f, a0 = 0.f;
        for (int j = 0; j < 128; ++j) {
            float f0 = pool[P_WF0 + j], f1 = pool[P_WF1 + j], fbv = pool[P_FB + j];
            kp += w0[j]*fbv; kc += w1[j]*fbv;
            u  += w0[j]*f0;  c1 += w0[j]*f1 + w1[j]*f0;  a0 += w1[j]*f1;
        }
        pool[P_Z0C + tid*6 + 0] = kp;
        pool[P_Z0C + tid*6 + 1] = kc;
        pool[P_Z0C + tid*6 + 2] = u;
        pool[P_Z0C + tid*6 + 3] = c1;
        pool[P_Z0C + tid*6 + 4] = a0;
    }
    // skip-init closed form: skip0 = SK + x1*SA + x0*SB
    if (tid < 2) {
        const float* wr = pool + P_WSKIPC + tid*128;
        float sk = pool[P_SKIPCB + tid], sa = 0.f, sb = 0.f;
        for (int j = 0; j < 128; ++j) {
            sk += wr[j]*pool[P_FB + j];
            sa += wr[j]*pool[P_WF0 + j];
            sb += wr[j]*pool[P_WF1 + j];
        }
        pool[P_SKC + tid*3 + 0] = sk;
        pool[P_SKC + tid*3 + 1] = sa;
        pool[P_SKC + tid*3 + 2] = sb;
    }
    __syncthreads();

    int e = 0;            // exchange epoch (uniform ++ order across all blocks)
    int er_pending = 0;   // epoch of most recent res publish
    int esk = 0;          // epoch of skip publish (set at l==19)

    for (int t = 0; t < TT; ++t) {
        // ---------------- per-chunk precompute ----------------
        if ((t & 63) == 0) {
            int te = t >> 6;
            for (int m = tid; m < 512; m += NTHR) {
                int b = m >> 6, j = m & 63;
                pool[P_CF + b*66 + j] = enc[(size_t)b*512 + j*8 + te];
            }
            __syncthreads();
            for (int m = tid; m < 640; m += NTHR) {
                int l = m >> 5, rem = m & 31, g = rem >> 3, b = rem & 7;
                int grow = (g < 2) ? (2*J + g) : (128 + 2*J + (g - 2));
                float acc = causal_b[l*256 + grow] + cond_b[l*256 + grow]
                          + pool[P_ZB + l*4 + g];
                const float* cw = cond_w + (size_t)(l*256 + grow)*64;
                const float* cf = pool + P_CF + b*66;
                for (int j = 0; j < 64; ++j) acc += cw[j]*cf[j];
                pool[P_CONDZ + l*32 + g*8 + b] = acc;
            }
            if (tid < 16) {
                int r = tid >> 3, b = tid & 7, row = 2*J + r;
                float acc = fc_b[row] + condf_b[row];
                const float* cw = condf_w + (size_t)row*64;
                const float* cf = pool + P_CF + b*66;
                for (int j = 0; j < 64; ++j) acc += cw[j]*cf[j];
                pool[P_SFC + r*8 + b] = acc;
            }
            __syncthreads();
        }

        // ---------------- h_0 closed form + immediate publish ----------------
        ++e; const int eh0 = e;
        {
            if (tid < 16) {
                int r = tid & 1, b = tid >> 1;
                float kf  = (t >= 1) ? 1.f : 0.f;
                float x0v = pool[P_XS + b];
                float x1v = pool[P_XS + 8 + b];
                float x2v = pool[P_XS + 16 + b];
                const float* zc = pool + P_Z0C;
                int g0 = r, g1 = 2 + r;
                float zg = kf*zc[g0*6+0] + zc[g0*6+1] + x2v*zc[g0*6+2]
                         + x1v*zc[g0*6+3] + x0v*zc[g0*6+4] + pool[P_CONDZ + g0*8 + b];
                float zo = kf*zc[g1*6+0] + zc[g1*6+1] + x2v*zc[g1*6+2]
                         + x1v*zc[g1*6+3] + x0v*zc[g1*6+4] + pool[P_CONDZ + g1*8 + b];
                pool[P_SL + r*8 + b] = (1.f/(1.f + expf(-zg))) * tanhf(zo);
            }
            publish16(xb + (size_t)(eh0 & 3)*768, J, pool + P_SL, eh0);
        }
        // res_0 full -> RESF buf0 (read at l=1 S1'; parity math matches)
        for (int m = tid; m < 1024; m += NTHR) {
            int b = m >> 7, r = m & 127;
            pool[P_RESF + b*132 + r] =
                pool[P_FB + r] + pool[P_XS + 8 + b]*pool[P_WF0 + r]
                               + pool[P_XS + b]    *pool[P_WF1 + r];
        }
        // skip init + r2 init (closed form)
        if (tid < 16) {
            int r = tid >> 3, b = tid & 7;
            float x0v = pool[P_XS + b], x1v = pool[P_XS + 8 + b];
            pool[P_SKACC + r*8 + b] = pool[P_SKC + r*3] + x1v*pool[P_SKC + r*3 + 1]
                                                        + x0v*pool[P_SKC + r*3 + 2];
            int row = 2*J + r;
            pool[P_R2 + r*8 + b] = pool[P_FB + row] + x1v*pool[P_WF0 + row]
                                                    + x0v*pool[P_WF1 + row];
        }

        // ---------------- layer loop: 2 barriers per layer ----------------
        for (int l = 0; l < LL; ++l) {
            const int par = l & 1;
            const int w = tid >> 6, lane = tid & 63;
            ull pf0 = 0, pf1 = 0, pf2 = 0, pf3 = 0;
            int ehh;
            if (l == 0) {
                ehh = eh0;
            } else {
                ++e; ehh = e;
                // S1': waves 0,1 compute (gate,out) pair, activate, publish in-wave
                if (w < 2) {
                    int r = w, b = lane >> 3, k = lane & 7;
                    const f4* wg = (const f4*)&pool[P_WC + (l*4 + r)*256];
                    const f4* wo = (const f4*)&pool[P_WC + (l*4 + 2 + r)*256];
                    const f4* fg = (const f4*)&pool[P_F + ((l-1)*4 + r)*128];
                    const f4* fo = (const f4*)&pool[P_F + ((l-1)*4 + 2 + r)*128];
                    const f4* pv = (const f4*)&pool[P_PREVF + b*132];
                    const f4* rs = (const f4*)&pool[P_RESF + ((l-1) & 1)*1056 + b*132];
                    const f4* hh = (const f4*)&pool[P_HF + ((l-1) & 1)*1056 + b*132];
                    float ag = 0.f, ao = 0.f;
                    #pragma unroll
                    for (int i = 0; i < 4; ++i) {
                        int j4 = k*4 + i;
                        f4 p = pv[j4], rr = rs[j4], h = hh[j4];
                        ag += dotf4(wg[j4], p) + dotf4(wg[32 + j4], rr) + dotf4(fg[j4], h);
                        ao += dotf4(wo[j4], p) + dotf4(wo[32 + j4], rr) + dotf4(fo[j4], h);
                    }
                    ag += __shfl_xor(ag,1); ag += __shfl_xor(ag,2); ag += __shfl_xor(ag,4);
                    ao += __shfl_xor(ao,1); ao += __shfl_xor(ao,2); ao += __shfl_xor(ao,4);
                    if (k == 0) {
                        float g = ag + pool[P_CONDZ + l*32 + r*8 + b];
                        float o = ao + pool[P_CONDZ + l*32 + (2+r)*8 + b];
                        pool[P_SL + r*8 + b] = (1.f/(1.f + expf(-g))) * tanhf(o);
                    }
                    if (lane < 3)
                        publish_half(xb + (size_t)(ehh & 3)*768, J, r,
                                     pool + P_SL + r*8, ehh, lane);
                }
            }
            // staging: waves 2,3 (parallel with S1')
            if (w >= 2) {
                int q = tid - 128;
                int r0 = q >> 6, i0 = (q & 63)*2;
                float2 v0 = *(const float2*)(res_w  + (size_t)(l*128 + 2*J + r0)*128 + i0);
                float2 v1 = *(const float2*)(skip_w + (size_t)(l*128 + 2*J + r0)*128 + i0);
                if (l <= 18) {
                    int d = c_dil[l+1];
                    if (t >= d) {
                        int slot = (t - d) & (2*d - 1);
                        const float* rp = ring + c_roff[l+1] + (size_t)slot*1024 + q*8;
                        pf0 = __hip_atomic_load((const ull*)rp,     __ATOMIC_RELAXED, __HIP_MEMORY_SCOPE_AGENT);
                        pf1 = __hip_atomic_load((const ull*)(rp+2), __ATOMIC_RELAXED, __HIP_MEMORY_SCOPE_AGENT);
                        pf2 = __hip_atomic_load((const ull*)(rp+4), __ATOMIC_RELAXED, __HIP_MEMORY_SCOPE_AGENT);
                        pf3 = __hip_atomic_load((const ull*)(rp+6), __ATOMIC_RELAXED, __HIP_MEMORY_SCOPE_AGENT);
                    }
                }
                *(float2*)&pool[P_WST + r0*128 + i0]       = v0;
                *(float2*)&pool[P_WST + 256 + r0*128 + i0] = v1;
            }
            // consume into parity buffers (no barrier: writers/readers disjoint)
            if (l == 0) {
                consume16(xb + (size_t)(ehh & 3)*768, ehh, pool + P_HF, false);
            } else if (l <= 18) {
                consume_pair(xb + (size_t)(er_pending & 3)*768, er_pending,
                             pool + P_RESF + par*1056,
                             xb + (size_t)(ehh & 3)*768, ehh,
                             pool + P_HF + par*1056);
            } else {
                consume16(xb + (size_t)(ehh & 3)*768, ehh, pool + P_HF + 1056, false);
            }
            __syncthreads();   // bar A
            // S10: dres slice (waves 0,1) + skip accum (waves 2,3)
            {
                int b = lane >> 3, k = lane & 7;
                int r = w & 1, isSkip = w >> 1;
                if (isSkip || l <= 18) {
                    const float* wr = pool + P_WST + (isSkip ? 256 : 0) + r*128;
                    const float* hh = pool + P_HF + par*1056 + b*132;
                    float acc = 0.f;
                    #pragma unroll
                    for (int i = 0; i < 16; ++i) { int j = k + 8*i; acc += wr[j]*hh[j]; }
                    acc += __shfl_xor(acc,1); acc += __shfl_xor(acc,2); acc += __shfl_xor(acc,4);
                    if (k == 0) {
                        if (isSkip) {
                            pool[P_SKACC + r*8 + b] += acc + pool[P_SKIPB + l*2 + r];
                        } else {
                            float v = pool[P_R2 + r*8 + b] + acc + pool[P_RESB + l*2 + r];
                            pool[P_R2 + r*8 + b] = v;
                            pool[P_SL + r*8 + b] = v;
                            int d = c_dil[l+1];
                            int slot = t & (2*d - 1);
                            float* wp = ring + c_roff[l+1] + (size_t)slot*1024 + b*128 + 2*J + r;
                            __hip_atomic_store(wp, v, __ATOMIC_RELAXED, __HIP_MEMORY_SCOPE_AGENT);
                        }
                    }
                }
            }
            // S10b: in-wave publishes
            {
                if (l <= 17) {
                    ++e; er_pending = e;
                    if (w < 2 && lane < 3)
                        publish_half(xb + (size_t)(e & 3)*768, J, w,
                                     pool + P_SL + w*8, e, lane);
                } else if (l == 19) {
                    ++e; esk = e;
                    if (w >= 2 && lane < 3)
                        publish_half(xb + (size_t)(e & 3)*768, J, w - 2,
                                     pool + P_SKACC + (w - 2)*8, e, lane);
                }
            }
            // S11: land prev prefetch (waves 2,3)
            if (w >= 2 && l <= 18) {
                int q = tid - 128, b = q >> 4, c = (q & 15)*8;
                union { ull u; float f[2]; } u0, u1, u2, u3;
                u0.u = pf0; u1.u = pf1; u2.u = pf2; u3.u = pf3;
                float* dp = pool + P_PREVF + b*132 + c;
                dp[0] = u0.f[0]; dp[1] = u0.f[1]; dp[2] = u1.f[0]; dp[3] = u1.f[1];
                dp[4] = u2.f[0]; dp[5] = u2.f[1]; dp[6] = u3.f[0]; dp[7] = u3.f[1];
            }
            __syncthreads();   // bar B
        }

        // ---------------- head ----------------
        consume16(xb + (size_t)(esk & 3)*768, esk, pool + P_HF, false);   // skip gather -> HF0
        __syncthreads();
        // fc: s = relu(skip).fc^T + sfc  (waves 0,1) + in-wave publish
        {
            int w = tid >> 6, lane = tid & 63, b = lane >> 3, k = lane & 7;
            if (w < 2) {
                const float* wr = pool + P_WFC + w*128;
                const float* sk = pool + P_HF + b*132;
                float acc = 0.f;
                #pragma unroll
                for (int i = 0; i < 16; ++i) { int j = k + 8*i; acc += wr[j]*fmaxf(sk[j], 0.f); }
                acc += __shfl_xor(acc,1); acc += __shfl_xor(acc,2); acc += __shfl_xor(acc,4);
                if (k == 0) pool[P_SL + w*8 + b] = acc + pool[P_SFC + w*8 + b];
            }
        }
        ++e;
        {
            int w = tid >> 6, lane = tid & 63;
            if (w < 2 && lane < 3)
                publish_half(xb + (size_t)(e & 3)*768, J, w, pool + P_SL + w*8, e, lane);
        }
        consume16(xb + (size_t)(e & 3)*768, e, pool + P_RESF, true);   // relu(s) -> RESF0
        __syncthreads();
        // logits rows + direct out-store + block-local argmax pair
        {
            int b = tid >> 5, g = (tid >> 3) & 3, k = tid & 7;
            const float* wr = pool + P_WLOG + g*128;
            const float* sv = pool + P_RESF + b*132;
            float acc = 0.f;
            #pragma unroll
            for (int i = 0; i < 16; ++i) { int j = k + 8*i; acc += wr[j]*sv[j]; }
            acc += __shfl_xor(acc,1); acc += __shfl_xor(acc,2); acc += __shfl_xor(acc,4);
            float v = acc + pool[P_LOGB + g];
            float best = (k == 0) ? v : -3.4e38f;
            int bi = 4*J + g;
            { float ov = __shfl_xor(best, 8);  int oi = __shfl_xor(bi, 8);
              if (ov > best || (ov == best && oi < bi)) { best = ov; bi = oi; } }
            { float ov = __shfl_xor(best, 16); int oi = __shfl_xor(bi, 16);
              if (ov > best || (ov == best && oi < bi)) { best = ov; bi = oi; } }
            if (k == 0) out[4096 + ((size_t)(t*BB + b))*256 + 4*J + g] = v;
            if ((tid & 31) == 0) { pool[P_SL + b] = best; pool[P_SL + 8 + b] = (float)bi; }
        }
        __syncthreads();
        ++e;
        publish16(xb + (size_t)(e & 3)*768, J, pool + P_SL, e);   // 64 (max,idx) pairs
        consume16(xb + (size_t)(e & 3)*768, e, pool + P_HF, false);
        __syncthreads();
        // final argmax reduce (idx-min tie-break == global first max) + x shift
        if (tid < 64) {
            int b = tid >> 3, j0 = tid & 7;
            float best = -3.4e38f; float bidx = 0.f;
            #pragma unroll
            for (int k2 = 0; k2 < 8; ++k2) {
                int j = j0*8 + k2;
                float v  = pool[P_HF + b*132 + 2*j];
                float id = pool[P_HF + b*132 + 2*j + 1];
                if (v > best || (v == best && id < bidx)) { best = v; bidx = id; }
            }
            #pragma unroll
            for (int m = 4; m >= 1; m >>= 1) {
                float ov = __shfl_xor(best, m); float oi = __shfl_xor(bidx, m);
                if (ov > best || (ov == best && oi < bidx)) { best = ov; bidx = oi; }
            }
            if (j0 == 0) {
                if (J == 0) out[t*BB + b] = bidx;
                pool[P_XS + 16 + b] = pool[P_XS + 8 + b];
                pool[P_XS + 8 + b]  = pool[P_XS + b];
                pool[P_XS + b]      = bidx*(1.f/255.f) - 0.5f;
            }
        }
        __syncthreads();
    }
}

// ============================================================
extern "C" void kernel_launch(void* const* d_in, const int* in_sizes, int n_in,
                              void* d_out, int out_size, void* d_ws, size_t ws_size,
                              hipStream_t stream) {
    const float* enc      = (const float*)d_in[0];
    const float* first_w  = (const float*)d_in[1];
    const float* first_b  = (const float*)d_in[2];
    const float* causal_w = (const float*)d_in[3];
    const float* causal_b = (const float*)d_in[4];
    const float* cond_w   = (const float*)d_in[5];
    const float* cond_b   = (const float*)d_in[6];
    const float* res_w    = (const float*)d_in[7];
    const float* res_b    = (const float*)d_in[8];
    const float* skip_w   = (const float*)d_in[9];
    const float* skip_b   = (const float*)d_in[10];
    const float* skipc_w  = (const float*)d_in[11];
    const float* skipc_b  = (const float*)d_in[12];
    const float* fc_w     = (const float*)d_in[13];
    const float* fc_b     = (const float*)d_in[14];
    const float* condf_w  = (const float*)d_in[15];
    const float* condf_b  = (const float*)d_in[16];
    const float* logits_w = (const float*)d_in[17];
    const float* logits_b = (const float*)d_in[18];

    float* wsf = (float*)d_ws;
    float* out = (float*)d_out;

    wn_gen<<<NBLK, NTHR, POOL_FL*4, stream>>>(
        enc, first_w, first_b, causal_w, causal_b, cond_w, cond_b,
        res_w, res_b, skip_w, skip_b, skipc_w, skipc_b, fc_w, fc_b,
        condf_w, condf_b, logits_w, logits_b, wsf, out);
}